// Round 9
// baseline (341.764 us; speedup 1.0000x reference)
//
#include <hip/hip_runtime.h>
#include <hip/hip_bf16.h>

#define M_TOK 8192
#define N_OUT 4096
#define K_IN  4096

typedef __attribute__((ext_vector_type(8))) short bf16x8;
typedef __attribute__((ext_vector_type(4))) float f32x4;
typedef unsigned short u16;

// fp32 -> bf16 RNE (finite inputs)
__device__ static inline u16 f2bf(float f) {
    union { float f; unsigned int u; } v; v.f = f;
    unsigned int u = v.u;
    u += 0x7FFFu + ((u >> 16) & 1u);
    return (u16)(u >> 16);
}

__device__ static inline void load_lds16(const void* g, void* l) {
    __builtin_amdgcn_global_load_lds(
        (const __attribute__((address_space(1))) unsigned int*)g,
        (__attribute__((address_space(3))) unsigned int*)l,
        16, 0, 0);
}

// ---------------- fused prep pass (memory-bound, ~HBM roofline) -----------
__global__ void prep_kernel(const float* __restrict__ x,
                            const float* __restrict__ mean,
                            const float* __restrict__ sigma,
                            const float* __restrict__ noise,
                            const int* __restrict__ smult,
                            u16* __restrict__ xb, u16* __restrict__ wb) {
    if (blockIdx.x < 2048) {
        const int n4 = (M_TOK * K_IN) / 4;
        int i = blockIdx.x * blockDim.x + threadIdx.x;
        const int stride = 2048 * 256;
        for (int e = i; e < n4; e += stride) {
            float4 v = reinterpret_cast<const float4*>(x)[e];
            ushort4 o;
            o.x = f2bf(v.x); o.y = f2bf(v.y); o.z = f2bf(v.z); o.w = f2bf(v.w);
            reinterpret_cast<ushort4*>(xb)[e] = o;
        }
    } else {
        const float sm = (float)(*smult);
        const int n4 = (N_OUT * K_IN) / 4;
        int i = (blockIdx.x - 2048) * blockDim.x + threadIdx.x;
        const int stride = 1024 * 256;
        for (int e = i; e < n4; e += stride) {
            float4 m = reinterpret_cast<const float4*>(mean)[e];
            float4 s = reinterpret_cast<const float4*>(sigma)[e];
            float4 z = reinterpret_cast<const float4*>(noise)[e];
            ushort4 o;
            o.x = f2bf(m.x * (1.0f + z.x * fabsf(s.x) * sm));
            o.y = f2bf(m.y * (1.0f + z.y * fabsf(s.y) * sm));
            o.z = f2bf(m.z * (1.0f + z.z * fabsf(s.z) * sm));
            o.w = f2bf(m.w * (1.0f + z.w * fabsf(s.w) * sm));
            reinterpret_cast<ushort4*>(wb)[e] = o;
        }
    }
}

// ------ 128x128 GEMM, 4 waves, 2 blocks/CU for cross-block LDS/MFMA overlap
// C[t][o] = sum_k A[t][k]*B[o][k] + bias[o]; A=[M][K] bf16, B=[N][K] bf16.
// LDS: [buf(2)][A(128x64) | B(128x64)] = 64 KiB -> 2 blocks/CU (160 KiB cap).
// Independent blocks' barriers decorrelate: block X's LDS burst overlaps
// block Y's MFMA cluster (m114 mechanism). 16B-slot swizzle slot^=(row&7)
// on global src of global_load_lds + on ds_read (measured 0 conflicts).
// One barrier per K-tile; VMC0 drains stage loads issued ~2000 cyc earlier.

#define BARM()   { __builtin_amdgcn_s_barrier(); asm volatile("" ::: "memory"); }
#define SCHED0() __builtin_amdgcn_sched_barrier(0)
#define VMC0()   asm volatile("s_waitcnt vmcnt(0)" ::: "memory")

#define LDA(KK) \
  _Pragma("unroll") for (int m_ = 0; m_ < 4; ++m_) \
    aR[m_] = *reinterpret_cast<const bf16x8*>(A_ + m_*1024 + aoff[KK]);

#define LDB(KK) \
  _Pragma("unroll") for (int n_ = 0; n_ < 4; ++n_) \
    bR[n_] = *reinterpret_cast<const bf16x8*>(B_ + n_*1024 + aoff[KK]);

#define MF16() \
  __builtin_amdgcn_s_setprio(1); \
  _Pragma("unroll") for (int m_ = 0; m_ < 4; ++m_) \
  _Pragma("unroll") for (int n_ = 0; n_ < 4; ++n_) \
    acc[m_][n_] = __builtin_amdgcn_mfma_f32_16x16x32_bf16( \
        aR[m_], bR[n_], acc[m_][n_], 0, 0, 0); \
  __builtin_amdgcn_s_setprio(0);

// stage one quarter (32 rows) of one operand; 256 threads x 16B = 4 KB/call
#define STAGE_OP(T, Q, BUF, GBASE, LOFF) { \
  const u16* g_ = (GBASE) + (size_t)((Q)*32 + srow) * K_IN + (T)*64 + sxcol; \
  load_lds16(g_, smem + (BUF)*16384 + (LOFF) + (Q)*2048 + tid*8); }

#define STAGE_ALL(T, BUF) \
  STAGE_OP(T, 0, BUF, Abase, 0)    STAGE_OP(T, 1, BUF, Abase, 0) \
  STAGE_OP(T, 2, BUF, Abase, 0)    STAGE_OP(T, 3, BUF, Abase, 0) \
  STAGE_OP(T, 0, BUF, Bbase, 8192) STAGE_OP(T, 1, BUF, Bbase, 8192) \
  STAGE_OP(T, 2, BUF, Bbase, 8192) STAGE_OP(T, 3, BUF, Bbase, 8192)

// One K-tile: stage t+1 -> WB; read RB (kk=0,1); 32 MFMA; gate; barrier.
#define TILE(T, RB, WB) { \
  const int tn_ = ((T) < 63) ? (T) + 1 : 63; \
  STAGE_ALL(tn_, WB); \
  SCHED0(); \
  const u16* A_ = smem + (RB)*16384 +        wr*4096; \
  const u16* B_ = smem + (RB)*16384 + 8192 + wc*4096; \
  { bf16x8 aR[4], bR[4]; \
    LDA(0); LDB(0); MF16(); \
    LDA(1); LDB(1); MF16(); } \
  VMC0(); BARM(); }

__global__ __launch_bounds__(256, 2)
void gemm_bias_kernel(const u16* __restrict__ A, const u16* __restrict__ B,
                      const float* __restrict__ bias, float* __restrict__ C) {
    __shared__ u16 smem[32768];   // 64 KiB

    const int tid   = threadIdx.x;
    const int lane  = tid & 63;
    const int wid   = tid >> 6;
    const int wr    = wid >> 1;      // 0..1 (M half of tile, 64 rows)
    const int wc    = wid & 1;       // 0..1 (N half of tile, 64 cols)
    const int la_lo = lane & 15;
    const int la_hi = lane >> 4;

    // T1 v3: 2048 blocks; xcd = bid&7 owns A-rows [xcd*8, xcd*8+8) for the
    // WHOLE kernel (A stays L2-hot); rounds r=0..3 sweep bn in 8-col strips.
    // Within a round: 64 concurrent blocks = 8bm x 8bn rect per XCD.
    const int bid = blockIdx.x;
    const int xcd = bid & 7;
    const int c   = bid >> 3;        // 0..255
    const int r   = c >> 6;          // 0..3
    const int s   = c & 63;
    const int bm  = xcd * 8 + (s & 7);    // 0..63
    const int bn  = r * 8 + (s >> 3);     // 0..31
    const int brow = bm * 128;
    const int bcol = bn * 128;

    const u16* Abase = A + (size_t)brow * K_IN;
    const u16* Bbase = B + (size_t)bcol * K_IN;

    // staging swizzle (measured 0 conflicts): row = Q*32+srow, slot^=(row&7)
    const int srow  = tid >> 3;          // 0..31
    const int sxcol = ((tid & 7) ^ (srow & 7)) * 8;

    // ds_read swizzled offsets per kk (measured 0 conflicts)
    const int xorr = la_lo & 7;
    int aoff[2];
    aoff[0] = la_lo * 64 + ((la_hi    ) ^ xorr) * 8;
    aoff[1] = la_lo * 64 + ((la_hi + 4) ^ xorr) * 8;

    f32x4 acc[4][4];
    #pragma unroll
    for (int m = 0; m < 4; ++m)
        #pragma unroll
        for (int n = 0; n < 4; ++n)
            acc[m][n] = (f32x4){0.f, 0.f, 0.f, 0.f};

    // Prologue: stage tile0 -> buf0; drain; barrier.
    STAGE_ALL(0, 0);
    VMC0(); BARM();

    // 64 K-tiles, unrolled x2 for static buffer alternation.
    for (int i = 0; i < 32; ++i) {
        TILE(2 * i,     0, 1);
        TILE(2 * i + 1, 1, 0);
    }

    // Epilogue: C/D layout col = lane&15, row = (lane>>4)*4 + rr; add bias
    const int crow0 = brow + wr * 64;
    const int ccol0 = bcol + wc * 64;
    #pragma unroll
    for (int n = 0; n < 4; ++n) {
        const int col = ccol0 + n * 16 + la_lo;
        const float bv = bias[col];
        #pragma unroll
        for (int m = 0; m < 4; ++m) {
            #pragma unroll
            for (int rr = 0; rr < 4; ++rr) {
                const int row = crow0 + m * 16 + la_hi * 4 + rr;
                C[(size_t)row * N_OUT + col] = acc[m][n][rr] + bv;
            }
        }
    }
}

extern "C" void kernel_launch(void* const* d_in, const int* in_sizes, int n_in,
                              void* d_out, int out_size, void* d_ws, size_t ws_size,
                              hipStream_t stream) {
    const float* x     = (const float*)d_in[0];
    const float* mean  = (const float*)d_in[1];
    const float* sigma = (const float*)d_in[2];
    const float* bias  = (const float*)d_in[3];
    const float* noise = (const float*)d_in[4];
    const int*   smult = (const int*)d_in[5];
    float* out = (float*)d_out;

    const size_t x_elems = (size_t)M_TOK * K_IN;
    const size_t w_elems = (size_t)N_OUT * K_IN;
    const size_t need = (x_elems + w_elems) * sizeof(u16);
    if (ws_size < need) return;

    u16* xb = (u16*)d_ws;
    u16* wb = xb + x_elems;

    prep_kernel<<<3072, 256, 0, stream>>>(x, mean, sigma, noise, smult, xb, wb);
    gemm_bias_kernel<<<2048, 256, 0, stream>>>(xb, wb, bias, out);
}